// Round 9
// baseline (920.605 us; speedup 1.0000x reference)
//
#include <hip/hip_runtime.h>

#define FFT_N   4096
#define THREADS 256
#define GRID_BLOCKS 512   // 256 CUs x 2 blocks/CU, persistent
#define NPAIRS 4096       // 8192 rows / 2 rows per pair

__device__ __forceinline__ float2 cmul(float2 a, float2 b) {
    return make_float2(a.x*b.x - a.y*b.y, a.x*b.y + a.y*b.x);
}
__device__ __forceinline__ float2 cadd(float2 a, float2 b){ return make_float2(a.x+b.x, a.y+b.y); }
__device__ __forceinline__ float2 csub(float2 a, float2 b){ return make_float2(a.x-b.x, a.y-b.y); }

// multiply by S*i  (S=-1: forward, S=+1: inverse)
template<int S>
__device__ __forceinline__ float2 muli(float2 z) {
    return (S < 0) ? make_float2(z.y, -z.x) : make_float2(-z.y, z.x);
}

// 4-point DFT: y[k] = sum_n a_n exp(S*2pi*i*n*k/4)
template<int S>
__device__ __forceinline__ void dft4(float2 a0, float2 a1, float2 a2, float2 a3,
                                     float2& y0, float2& y1, float2& y2, float2& y3) {
    float2 e0 = cadd(a0, a2), e1 = cadd(a1, a3);
    float2 o0 = csub(a0, a2), o1 = muli<S>(csub(a1, a3));
    y0 = cadd(e0, e1); y2 = csub(e0, e1);
    y1 = cadd(o0, o1); y3 = csub(o0, o1);
}

// 16-point DFT in registers: a[k] <- sum_n a[n] exp(S*2pi*i*n*k/16)
template<int S>
__device__ __forceinline__ void dft16(float2* a) {
    const float C1 = 0.92387953251128674f;   // cos(pi/8)
    const float S1 = 0.38268343236508978f;   // sin(pi/8)
    const float R2 = 0.70710678118654752f;
    const float sg = (S < 0) ? -1.0f : 1.0f;
    const float2 w1 = make_float2( C1,  sg*S1);
    const float2 w2 = make_float2( R2,  sg*R2);
    const float2 w3 = make_float2( S1,  sg*C1);
    const float2 w6 = make_float2(-R2,  sg*R2);
    const float2 w9 = make_float2(-C1, -sg*S1);
    float2 t[16];
    dft4<S>(a[0], a[4], a[8],  a[12], t[0],  t[1],  t[2],  t[3]);
    dft4<S>(a[1], a[5], a[9],  a[13], t[4],  t[5],  t[6],  t[7]);
    dft4<S>(a[2], a[6], a[10], a[14], t[8],  t[9],  t[10], t[11]);
    dft4<S>(a[3], a[7], a[11], a[15], t[12], t[13], t[14], t[15]);
    t[5]  = cmul(t[5],  w1);  t[6]  = cmul(t[6],  w2);  t[7]  = cmul(t[7],  w3);
    t[9]  = cmul(t[9],  w2);  t[10] = muli<S>(t[10]);   t[11] = cmul(t[11], w6);
    t[13] = cmul(t[13], w3);  t[14] = cmul(t[14], w6);  t[15] = cmul(t[15], w9);
    dft4<S>(t[0], t[4], t[8],  t[12], a[0], a[4], a[8],  a[12]);
    dft4<S>(t[1], t[5], t[9],  t[13], a[1], a[5], a[9],  a[13]);
    dft4<S>(t[2], t[6], t[10], t[14], a[2], a[6], a[10], a[14]);
    dft4<S>(t[3], t[7], t[11], t[15], a[3], a[7], a[11], a[15]);
}

// R0[k],R1[k] *= exp(S*2pi*i*p*k/M), k=1..15. One sincos + tree powering,
// twiddle table SHARED between the two rows (computed once).
template<int S>
__device__ __forceinline__ void twiddle_apply2(float2* R0, float2* R1, int p, float invM) {
    float ang = 6.283185307179586f * (float)p * invM;
    if (S < 0) ang = -ang;
    float s, c;
    __sincosf(ang, &s, &c);
    float2 w[16];
    w[1] = make_float2(c, s);
    w[2] = cmul(w[1], w[1]);
    w[3] = cmul(w[2], w[1]);
    w[4] = cmul(w[2], w[2]);
    #pragma unroll
    for (int k = 5; k < 16; ++k) w[k] = cmul(w[k-4], w[4]);
    #pragma unroll
    for (int k = 1; k < 16; ++k) {
        R0[k] = cmul(R0[k], w[k]);
        R1[k] = cmul(R1[k], w[k]);
    }
}

// Swizzle on 16B (float4) slot index: bits 0..2 ^= bits 4..6.
// Conflict-free for all access patterns used (stride-256, stride-16-in-256,
// contiguous-16); preserves 16-slot-group membership so wave-local exchanges
// stay wave-local. Involution -> bijective on [0,4096).
__device__ __forceinline__ int swz16(int i) { return i ^ ((i >> 4) & 7); }

// Wave-local LDS fence (exchange entirely within 16-thread groups).
__device__ __forceinline__ void wave_lds_fence() {
    asm volatile("s_waitcnt lgkmcnt(0)" ::: "memory");
}

__global__ __launch_bounds__(THREADS, 2) void afdf_fft_kernel(
    const float* __restrict__ x,   // (B, 4096, 2)
    const float* __restrict__ A,   // (1, 4096, 2)
    const float* __restrict__ D,   // (1, 4096, 2)
    float* __restrict__ out)       // (B, 4096, 2)
{
    // One float4 slot per point: (row0.re, row0.im, row1.re, row1.im).
    // 4096 * 16 B = 64 KiB -> 2 blocks/CU. All LDS traffic is b128.
    __shared__ __align__(16) float4 sh[FFT_N];

    const int t = threadIdx.x;
    const float2* __restrict__ Ac = (const float2*)A;
    const float2* __restrict__ Dc = (const float2*)D;

    // ---- Loop-invariant parameters in registers (loaded once per block) ----
    float2 aA[16];     // A-scale, phase-A layout
    float2 dreg[16];   // D-scale with 1/N folded, phase-C layout
    {
        #pragma unroll
        for (int n = 0; n < 16; ++n) aA[n] = Ac[t + 256*n];
        const int k1 = t >> 4, k2 = t & 15;
        const float inv = 1.0f / 4096.0f;
        #pragma unroll
        for (int k3 = 0; k3 < 16; ++k3) {
            float2 d = Dc[256*k3 + 16*k2 + k1];
            dreg[k3] = make_float2(d.x*inv, d.y*inv);
        }
    }

    // ---- Prologue: prefetch first pair's x into registers ----
    float2 px0[16], px1[16];
    {
        const float2* __restrict__ xr0 = (const float2*)x + (size_t)blockIdx.x * 2 * FFT_N;
        const float2* __restrict__ xr1 = xr0 + FFT_N;
        #pragma unroll
        for (int n = 0; n < 16; ++n) {
            px0[n] = xr0[t + 256*n];
            px1[n] = xr1[t + 256*n];
        }
    }

    float2 r0[16], r1[16];

    #pragma unroll 1
    for (int pair = blockIdx.x; pair < NPAIRS; pair += GRID_BLOCKS) {
        float2* __restrict__ o0 = (float2*)out + (size_t)pair * 2 * FFT_N;
        float2* __restrict__ o1 = o0 + FFT_N;

        // ---- Phase A: A-scale (from regs) + S1 (stride-256) ----
        {
            #pragma unroll
            for (int n = 0; n < 16; ++n) {
                r0[n] = make_float2(aA[n].x*px0[n].x, aA[n].y*px0[n].y);
                r1[n] = make_float2(aA[n].x*px1[n].x, aA[n].y*px1[n].y);
            }
            dft16<-1>(r0);
            dft16<-1>(r1);
            twiddle_apply2<-1>(r0, r1, t, 1.0f/4096.0f);    // W4096^{t*k}
            __syncthreads();   // WAR: prev iter's phase-E LDS reads complete
            #pragma unroll
            for (int k = 0; k < 16; ++k)
                sh[swz16(t + 256*k)] = make_float4(r0[k].x, r0[k].y, r1[k].x, r1[k].y);
        }
        __syncthreads();   // A->B exchange (block-wide)

        // ---- Phase B: S2 (within 256-blocks, stride 16) ----
        {
            const int b = t >> 4, p2 = t & 15, base = b*256;
            #pragma unroll
            for (int n = 0; n < 16; ++n) {
                float4 v = sh[swz16(base + p2 + 16*n)];
                r0[n] = make_float2(v.x, v.y);
                r1[n] = make_float2(v.z, v.w);
            }
            dft16<-1>(r0);
            dft16<-1>(r1);
            twiddle_apply2<-1>(r0, r1, p2, 1.0f/256.0f);    // W256^{p2*k}
            #pragma unroll
            for (int k = 0; k < 16; ++k)
                sh[swz16(base + p2 + 16*k)] = make_float4(r0[k].x, r0[k].y, r1[k].x, r1[k].y);
        }
        // B->C exchange is within 16-thread groups -> wave-local fence
        wave_lds_fence();

        // ---- Phase C: S3 + D-scale (1/N folded) + S3^-1, in registers ----
        {
            const int base = 16*t;
            #pragma unroll
            for (int n = 0; n < 16; ++n) {
                float4 v = sh[swz16(base + n)];
                r0[n] = make_float2(v.x, v.y);
                r1[n] = make_float2(v.z, v.w);
            }
            dft16<-1>(r0);
            dft16<-1>(r1);
            #pragma unroll
            for (int k3 = 0; k3 < 16; ++k3) {
                r0[k3] = make_float2(dreg[k3].x*r0[k3].x, dreg[k3].y*r0[k3].y);
                r1[k3] = make_float2(dreg[k3].x*r1[k3].x, dreg[k3].y*r1[k3].y);
            }
            dft16<+1>(r0);
            dft16<+1>(r1);
            #pragma unroll
            for (int n = 0; n < 16; ++n)
                sh[swz16(base + n)] = make_float4(r0[n].x, r0[n].y, r1[n].x, r1[n].y);
        }
        // C->D exchange: wave-local fence
        wave_lds_fence();

        // ---- Prefetch next pair's x (issued here; consumed next phase A).
        //      ~2 phases (D+E) of compute cover the HBM latency. ----
        {
            const int np = pair + GRID_BLOCKS;
            if (np < NPAIRS) {
                const float2* __restrict__ nx0 = (const float2*)x + (size_t)np * 2 * FFT_N;
                const float2* __restrict__ nx1 = nx0 + FFT_N;
                #pragma unroll
                for (int n = 0; n < 16; ++n) {
                    px0[n] = nx0[t + 256*n];
                    px1[n] = nx1[t + 256*n];
                }
            }
        }

        // ---- Phase D: S2^-1 (un-twiddle, conj DFT, stride 16) ----
        {
            const int b = t >> 4, p2 = t & 15, base = b*256;
            #pragma unroll
            for (int k = 0; k < 16; ++k) {
                float4 v = sh[swz16(base + p2 + 16*k)];
                r0[k] = make_float2(v.x, v.y);
                r1[k] = make_float2(v.z, v.w);
            }
            twiddle_apply2<+1>(r0, r1, p2, 1.0f/256.0f);
            dft16<+1>(r0);
            dft16<+1>(r1);
            #pragma unroll
            for (int n = 0; n < 16; ++n)
                sh[swz16(base + p2 + 16*n)] = make_float4(r0[n].x, r0[n].y, r1[n].x, r1[n].y);
        }
        __syncthreads();   // D->E exchange (block-wide)

        // ---- Phase E: S1^-1 + store (1/N already folded into D) ----
        {
            #pragma unroll
            for (int k = 0; k < 16; ++k) {
                float4 v = sh[swz16(t + 256*k)];
                r0[k] = make_float2(v.x, v.y);
                r1[k] = make_float2(v.z, v.w);
            }
            twiddle_apply2<+1>(r0, r1, t, 1.0f/4096.0f);
            dft16<+1>(r0);
            dft16<+1>(r1);
            #pragma unroll
            for (int n1 = 0; n1 < 16; ++n1) {
                o0[t + 256*n1] = r0[n1];
                o1[t + 256*n1] = r1[n1];
            }
        }
    }
}

extern "C" void kernel_launch(void* const* d_in, const int* in_sizes, int n_in,
                              void* d_out, int out_size, void* d_ws, size_t ws_size,
                              hipStream_t stream) {
    (void)in_sizes; (void)n_in; (void)out_size; (void)d_ws; (void)ws_size;
    const float* x = (const float*)d_in[0];
    const float* A = (const float*)d_in[1];
    const float* D = (const float*)d_in[2];
    float* out = (float*)d_out;

    // persistent: 512 blocks (2/CU), each processes 8 row-pairs
    afdf_fft_kernel<<<dim3(GRID_BLOCKS), dim3(THREADS), 0, stream>>>(x, A, D, out);
}

// Round 10
// 455.318 us; speedup vs baseline: 2.0219x; 2.0219x over previous
//
#include <hip/hip_runtime.h>

#define FFT_N   4096
#define THREADS 256

// Complex as a clang ext-vector: arithmetic on cf2 lowers to CDNA packed-FP32
// (v_pk_add_f32 / v_pk_mul_f32 / v_pk_fma_f32) -> ~half the VALU instructions
// of scalar .x/.y component math for the add-heavy DFT butterflies.
typedef float cf2 __attribute__((ext_vector_type(2)));

__device__ __forceinline__ cf2 mkc(float x, float y) { cf2 r; r.x = x; r.y = y; return r; }

// (a.x*b.x - a.y*b.y, a.x*b.y + a.y*b.x) = a.x*b + (-a.y,a.y)*b.yx
__device__ __forceinline__ cf2 cmul(cf2 a, cf2 b) {
    return a.x * b + mkc(-a.y, a.y) * b.yx;
}

// multiply by S*i  (S=-1: forward, S=+1: inverse)
template<int S>
__device__ __forceinline__ cf2 muli(cf2 z) {
    return (S < 0) ? mkc(z.y, -z.x) : mkc(-z.y, z.x);
}

// 4-point DFT: y[k] = sum_n a_n exp(S*2pi*i*n*k/4)
template<int S>
__device__ __forceinline__ void dft4(cf2 a0, cf2 a1, cf2 a2, cf2 a3,
                                     cf2& y0, cf2& y1, cf2& y2, cf2& y3) {
    cf2 e0 = a0 + a2, e1 = a1 + a3;
    cf2 o0 = a0 - a2, o1 = muli<S>(a1 - a3);
    y0 = e0 + e1; y2 = e0 - e1;
    y1 = o0 + o1; y3 = o0 - o1;
}

// 16-point DFT in registers: a[k] <- sum_n a[n] exp(S*2pi*i*n*k/16)
template<int S>
__device__ __forceinline__ void dft16(cf2* a) {
    const float C1 = 0.92387953251128674f;   // cos(pi/8)
    const float S1 = 0.38268343236508978f;   // sin(pi/8)
    const float R2 = 0.70710678118654752f;
    const float sg = (S < 0) ? -1.0f : 1.0f;
    const cf2 w1 = mkc( C1,  sg*S1);
    const cf2 w2 = mkc( R2,  sg*R2);
    const cf2 w3 = mkc( S1,  sg*C1);
    const cf2 w6 = mkc(-R2,  sg*R2);
    const cf2 w9 = mkc(-C1, -sg*S1);
    cf2 t[16];
    dft4<S>(a[0], a[4], a[8],  a[12], t[0],  t[1],  t[2],  t[3]);
    dft4<S>(a[1], a[5], a[9],  a[13], t[4],  t[5],  t[6],  t[7]);
    dft4<S>(a[2], a[6], a[10], a[14], t[8],  t[9],  t[10], t[11]);
    dft4<S>(a[3], a[7], a[11], a[15], t[12], t[13], t[14], t[15]);
    t[5]  = cmul(t[5],  w1);  t[6]  = cmul(t[6],  w2);  t[7]  = cmul(t[7],  w3);
    t[9]  = cmul(t[9],  w2);  t[10] = muli<S>(t[10]);   t[11] = cmul(t[11], w6);
    t[13] = cmul(t[13], w3);  t[14] = cmul(t[14], w6);  t[15] = cmul(t[15], w9);
    dft4<S>(t[0], t[4], t[8],  t[12], a[0], a[4], a[8],  a[12]);
    dft4<S>(t[1], t[5], t[9],  t[13], a[1], a[5], a[9],  a[13]);
    dft4<S>(t[2], t[6], t[10], t[14], a[2], a[6], a[10], a[14]);
    dft4<S>(t[3], t[7], t[11], t[15], a[3], a[7], a[11], a[15]);
}

// R0[k],R1[k] *= exp(S*2pi*i*p*k/M), k=1..15. One sincos + tree powering
// (dep depth ~5 cmuls), twiddle table SHARED between the two rows.
template<int S>
__device__ __forceinline__ void twiddle_apply2(cf2* R0, cf2* R1, int p, float invM) {
    float ang = 6.283185307179586f * (float)p * invM;
    if (S < 0) ang = -ang;
    float s, c;
    __sincosf(ang, &s, &c);
    cf2 w[16];
    w[1] = mkc(c, s);
    w[2] = cmul(w[1], w[1]);
    w[3] = cmul(w[2], w[1]);
    w[4] = cmul(w[2], w[2]);
    #pragma unroll
    for (int k = 5; k < 16; ++k) w[k] = cmul(w[k-4], w[4]);
    #pragma unroll
    for (int k = 1; k < 16; ++k) {
        R0[k] = cmul(R0[k], w[k]);
        R1[k] = cmul(R1[k], w[k]);
    }
}

// Swizzle on 16B (float4) slot index: bits 0..2 ^= bits 4..6.
// Conflict-free for all access patterns used (stride-256, stride-16-in-256,
// contiguous-16); preserves 16-slot-group membership. Involution -> bijective.
__device__ __forceinline__ int swz16(int i) { return i ^ ((i >> 4) & 7); }

__global__ __launch_bounds__(THREADS, 2) void afdf_fft_kernel(
    const float* __restrict__ x,   // (B, 4096, 2)
    const float* __restrict__ A,   // (1, 4096, 2)
    const float* __restrict__ D,   // (1, 4096, 2)
    float* __restrict__ out)       // (B, 4096, 2)
{
    // One float4 slot per point: (row0.re, row0.im, row1.re, row1.im).
    // 4096 * 16 B = 64 KiB -> 2 blocks/CU. All LDS traffic is b128.
    __shared__ __align__(16) float4 sh[FFT_N];

    const int t = threadIdx.x;
    const size_t rb = (size_t)blockIdx.x * 2 * FFT_N;
    const cf2* __restrict__ xr0 = (const cf2*)x + rb;
    const cf2* __restrict__ xr1 = xr0 + FFT_N;
    const cf2* __restrict__ Ac  = (const cf2*)A;
    const cf2* __restrict__ Dc  = (const cf2*)D;
    cf2* __restrict__ o0        = (cf2*)out + rb;
    cf2* __restrict__ o1        = o0 + FFT_N;

    cf2 r0[16], r1[16];

    // ---- Phase A: global load + A-scale + S1 (stride-256), both rows ----
    {
        const int p = t;
        #pragma unroll
        for (int n = 0; n < 16; ++n) {
            cf2 a = Ac[p + 256*n];              // shared between rows
            r0[n] = a * xr0[p + 256*n];         // elementwise scale (pk_mul)
            r1[n] = a * xr1[p + 256*n];
        }
        dft16<-1>(r0);
        dft16<-1>(r1);
        twiddle_apply2<-1>(r0, r1, p, 1.0f/4096.0f);    // W4096^{p*k}
        #pragma unroll
        for (int k = 0; k < 16; ++k)
            sh[swz16(p + 256*k)] = make_float4(r0[k].x, r0[k].y, r1[k].x, r1[k].y);
    }
    __syncthreads();

    // ---- Phase B: S2 (within 256-blocks, stride 16) ----
    {
        const int b = t >> 4, p2 = t & 15, base = b*256;
        #pragma unroll
        for (int n = 0; n < 16; ++n) {
            float4 v = sh[swz16(base + p2 + 16*n)];
            r0[n] = mkc(v.x, v.y);
            r1[n] = mkc(v.z, v.w);
        }
        dft16<-1>(r0);
        dft16<-1>(r1);
        twiddle_apply2<-1>(r0, r1, p2, 1.0f/256.0f);    // W256^{p2*k}
        #pragma unroll
        for (int k = 0; k < 16; ++k)
            sh[swz16(base + p2 + 16*k)] = make_float4(r0[k].x, r0[k].y, r1[k].x, r1[k].y);
    }
    __syncthreads();

    // ---- Phase C: S3 + D-scale (1/N folded) + S3^-1, in registers ----
    {
        const int base = 16*t;
        #pragma unroll
        for (int n = 0; n < 16; ++n) {
            float4 v = sh[swz16(base + n)];
            r0[n] = mkc(v.x, v.y);
            r1[n] = mkc(v.z, v.w);
        }
        dft16<-1>(r0);
        dft16<-1>(r1);
        // slot k3 holds frequency q = 256*k3 + 16*k2 + k1
        const int k1 = t >> 4, k2 = t & 15;
        const float inv = 1.0f / 4096.0f;
        #pragma unroll
        for (int k3 = 0; k3 < 16; ++k3) {
            cf2 d = Dc[256*k3 + 16*k2 + k1] * inv;      // shared between rows
            r0[k3] = d * r0[k3];                        // elementwise (pk_mul)
            r1[k3] = d * r1[k3];
        }
        dft16<+1>(r0);
        dft16<+1>(r1);
        #pragma unroll
        for (int n = 0; n < 16; ++n)
            sh[swz16(base + n)] = make_float4(r0[n].x, r0[n].y, r1[n].x, r1[n].y);
    }
    __syncthreads();

    // ---- Phase D: S2^-1 (un-twiddle, conj DFT, stride 16) ----
    {
        const int b = t >> 4, p2 = t & 15, base = b*256;
        #pragma unroll
        for (int k = 0; k < 16; ++k) {
            float4 v = sh[swz16(base + p2 + 16*k)];
            r0[k] = mkc(v.x, v.y);
            r1[k] = mkc(v.z, v.w);
        }
        twiddle_apply2<+1>(r0, r1, p2, 1.0f/256.0f);
        dft16<+1>(r0);
        dft16<+1>(r1);
        #pragma unroll
        for (int n = 0; n < 16; ++n)
            sh[swz16(base + p2 + 16*n)] = make_float4(r0[n].x, r0[n].y, r1[n].x, r1[n].y);
    }
    __syncthreads();

    // ---- Phase E: S1^-1 + store (normalization folded into D) ----
    {
        const int p = t;
        #pragma unroll
        for (int k = 0; k < 16; ++k) {
            float4 v = sh[swz16(p + 256*k)];
            r0[k] = mkc(v.x, v.y);
            r1[k] = mkc(v.z, v.w);
        }
        twiddle_apply2<+1>(r0, r1, p, 1.0f/4096.0f);
        dft16<+1>(r0);
        dft16<+1>(r1);
        #pragma unroll
        for (int n1 = 0; n1 < 16; ++n1) {
            o0[p + 256*n1] = r0[n1];
            o1[p + 256*n1] = r1[n1];
        }
    }
}

extern "C" void kernel_launch(void* const* d_in, const int* in_sizes, int n_in,
                              void* d_out, int out_size, void* d_ws, size_t ws_size,
                              hipStream_t stream) {
    (void)in_sizes; (void)n_in; (void)out_size; (void)d_ws; (void)ws_size;
    const float* x = (const float*)d_in[0];
    const float* A = (const float*)d_in[1];
    const float* D = (const float*)d_in[2];
    float* out = (float*)d_out;

    // 8192 rows, 2 rows per block
    afdf_fft_kernel<<<dim3(4096), dim3(THREADS), 0, stream>>>(x, A, D, out);
}